// Round 1
// 958.159 us; speedup vs baseline: 1.0260x; 1.0260x over previous
//
#include <hip/hip_runtime.h>
#include <cstdint>
#include <cstddef>

#define NNODES   10000
#define FD       128      // feature dim (conv length)
#define KTOP     8
#define MAXDEG   32
#define OUT_CH   128
#define XOUT     120      // FD - KTOP

typedef __attribute__((ext_vector_type(8))) short short8;
typedef __attribute__((ext_vector_type(4))) float f32x4;

// sel^T rows: 24 ushorts (48 B) -> c0 in {0,8} chunks are 16B aligned,
// 12 dwords/row -> bank shift 12 per row -> balanced LDS banks.
#define SELT_STRIDE 24
#define SELT_ROWS   144   // rows 128..143 are zero pad (n + t can reach 136)

#define WS_NEEDED ((size_t)NNODES * MAXDEG * 4 + (size_t)NNODES * 4)

__device__ __forceinline__ unsigned short f2bf(float f) {
    union { float f; unsigned u; } cv; cv.f = f;
    unsigned u = cv.u;
    u += 0x7FFFu + ((u >> 16) & 1u);   // round-to-nearest-even
    return (unsigned short)(u >> 16);
}

// lgkm-only barrier: orders LDS cross-wave WITHOUT draining vmcnt, so
// in-flight output stores (prev node) and gather loads (next node) keep
// flying across the per-node barriers. asm "memory" sandwich pins LDS ops
// on the correct side (rule #18-style code-motion guard).
#define BAR_LGKM() do {                                        \
    asm volatile("s_waitcnt lgkmcnt(0)" ::: "memory");         \
    __builtin_amdgcn_s_barrier();                              \
    asm volatile("" ::: "memory");                             \
} while (0)

// ---------------------------------------------------------------------------
// Kernel A: adjacency scan. One wave per row; 400 MB pure streaming read at
// full occupancy. Emits compact neighbor list (pad 0) + count per row.
// ---------------------------------------------------------------------------
#define CHK4(v, base) do {                                                        \
    if ((v).x == 1) { int _p = atomicAdd(&s_cnt[wv], 1); if (_p < MAXDEG) s_nbr[wv][_p] = 4 * (base) + 0; } \
    if ((v).y == 1) { int _p = atomicAdd(&s_cnt[wv], 1); if (_p < MAXDEG) s_nbr[wv][_p] = 4 * (base) + 1; } \
    if ((v).z == 1) { int _p = atomicAdd(&s_cnt[wv], 1); if (_p < MAXDEG) s_nbr[wv][_p] = 4 * (base) + 2; } \
    if ((v).w == 1) { int _p = atomicAdd(&s_cnt[wv], 1); if (_p < MAXDEG) s_nbr[wv][_p] = 4 * (base) + 3; } \
} while (0)

__global__ __launch_bounds__(256, 8)
void lgcl_scan(const int* __restrict__ adj, int* __restrict__ nbr,
               int* __restrict__ cnt)
{
    __shared__ int s_nbr[4][MAXDEG];
    __shared__ int s_cnt[4];
    const int lane = threadIdx.x & 63;
    const int wv   = threadIdx.x >> 6;
    const int row  = blockIdx.x * 4 + wv;     // grid = 2500 -> rows 0..9999 exactly

    if (lane == 0) s_cnt[wv] = 0;
    __syncthreads();

    const int4* arow = (const int4*)(adj + (size_t)row * NNODES);
    // 2500 int4 per row = 9*256 + 192 + 4. Keep 4 loads in flight per lane.
    int i = lane;
#pragma unroll 1
    for (int c = 0; c < 9; ++c) {
        int4 v0 = arow[i];
        int4 v1 = arow[i + 64];
        int4 v2 = arow[i + 128];
        int4 v3 = arow[i + 192];
        CHK4(v0, i); CHK4(v1, i + 64); CHK4(v2, i + 128); CHK4(v3, i + 192);
        i += 256;
    }
    {   // i = lane + 2304
        int4 v0 = arow[i];
        int4 v1 = arow[i + 64];
        int4 v2 = arow[i + 128];
        CHK4(v0, i); CHK4(v1, i + 64); CHK4(v2, i + 128);
        i += 192;                               // lane + 2496
    }
    if (i < NNODES / 4) { int4 v0 = arow[i]; CHK4(v0, i); }

    __syncthreads();
    int c = s_cnt[wv]; if (c > MAXDEG) c = MAXDEG;
    if (lane < MAXDEG)
        nbr[(size_t)row * MAXDEG + lane] = (lane < c) ? s_nbr[wv][lane] : 0;
    if (lane == 0) cnt[row] = c;
}

// ---------------------------------------------------------------------------
// Kernel B: gather + per-column top-8 + conv-as-MFMA + store.
// 2-deep pipeline: neighbor lists prefetched 2 nodes ahead (LDS dbuf),
// feature gather staged global->reg (issued before topk) -> LDS (written
// after bar2, before MFMA) 1 node ahead. Barriers are lgkm-only.
// ---------------------------------------------------------------------------
__global__ __launch_bounds__(256, 2)
void lgcl_conv(const float* __restrict__ nf, const int* __restrict__ nbr,
               const int* __restrict__ cnt, const float* __restrict__ cw,
               const float* __restrict__ cb, float* __restrict__ out)
{
    __shared__ float s_g[2 * MAXDEG * FD];                       // 32 KB dbuf
    __shared__ unsigned short s_selT[SELT_ROWS * SELT_STRIDE];   // 6.75 KB
    __shared__ int s_nl[2][40];                                  // nbr list + cnt dbuf

    const int tid = threadIdx.x;
    const int lane = tid & 63;
    const int wv  = tid >> 6;   // wave 0..3
    const int q   = lane >> 4;  // quad within wave
    const int n16 = lane & 15;
    const int mh  = wv >> 1;    // m-half of C tile grid
    const int nh  = wv & 1;     // n-half
    const int gj  = tid >> 3;   // gather row 0..31
    const int gl  = tid & 7;    // gather col-chunk

    // ---- one-time per block: A fragments (weights as bf16) + bias ----
    // k-mapping: k = t*16 + c  (t=conv tap 0..8, c=channel 0..8; rest zero)
    // A[m=lane&15][k = 32*s + q*8 + j]  ->  t = 2s + (q>>1), c = (q&1)*8 + j
    short8 afrag[4][5];
#pragma unroll
    for (int mt = 0; mt < 4; ++mt) {
        const int o = (mh * 4 + mt) * 16 + n16;
#pragma unroll
        for (int s = 0; s < 5; ++s) {
            const int t = 2 * s + (q >> 1);
            const int c0 = (q & 1) * 8;
            short8 a;
#pragma unroll
            for (int j = 0; j < 8; ++j) {
                const int c = c0 + j;
                float v = 0.0f;
                if (c <= 8 && t <= 8) v = cw[(o * 9 + c) * 9 + t];
                a[j] = (short)f2bf(v);
            }
            afrag[mt][s] = a;
        }
    }
    f32x4 bias[4];
#pragma unroll
    for (int mt = 0; mt < 4; ++mt) {
        const int o = (mh * 4 + mt) * 16 + q * 4;   // C row = q*4 + reg
        f32x4 b;
        b[0] = cb[o]; b[1] = cb[o + 1]; b[2] = cb[o + 2]; b[3] = cb[o + 3];
        bias[mt] = b;
    }

    // zero the pad rows (128..143) of selT once per block
    if (tid >= 128 && tid < 128 + (SELT_ROWS - FD)) {
        uint4* p = (uint4*)&s_selT[tid * SELT_STRIDE];
        p[0] = make_uint4(0, 0, 0, 0);
        p[1] = make_uint4(0, 0, 0, 0);
        p[2] = make_uint4(0, 0, 0, 0);
    }

    const int G   = gridDim.x;
    const int bid = blockIdx.x;
    int   pb    = 0;
    float selfv = 0.0f;

    // ---- prologue: lists(n0, n1) -> LDS; gather(n0) -> s_g[0]; self(n0) ----
    {
        const int n0 = bid;                       // grid 512 < NNODES: valid
        int n1 = n0 + G; if (n1 >= NNODES) n1 = n0;
        if (tid < 33) {
            s_nl[0][tid] = (tid < 32) ? nbr[(size_t)n0 * MAXDEG + tid] : cnt[n0];
            s_nl[1][tid] = (tid < 32) ? nbr[(size_t)n1 * MAXDEG + tid] : cnt[n1];
        }
        if (tid < FD) selfv = nf[(size_t)n0 * FD + tid];
        __syncthreads();
        const int nidx = s_nl[0][gj];
        const float4* gs = (const float4*)(nf + (size_t)nidx * FD);
        float4 a0 = gs[gl], a1 = gs[gl + 8], a2 = gs[gl + 16], a3 = gs[gl + 24];
        float4* gd = (float4*)(s_g + gj * FD);
        gd[gl] = a0; gd[gl + 8] = a1; gd[gl + 16] = a2; gd[gl + 24] = a3;
    }

    for (int node = bid; node < NNODES; node += G) {
        BAR_LGKM();   // bar1: gather(node) + list writes visible to all waves

        int n1 = node + G;     if (n1 >= NNODES) n1 = node;
        int n2 = node + 2 * G; if (n2 >= NNODES) n2 = n1;

        // prefetch list(node+2G) -> regs (LDS write deferred past bar2)
        int nlv = 0;
        if (tid < 33) nlv = (tid < 32) ? nbr[(size_t)n2 * MAXDEG + tid] : cnt[n2];

        // issue gather(node+G) -> regs; consumed by ds_write after bar2
        const int nidx = s_nl[pb ^ 1][gj];
        const float4* gs = (const float4*)(nf + (size_t)nidx * FD);
        float4 a0 = gs[gl], a1 = gs[gl + 8], a2 = gs[gl + 16], a3 = gs[gl + 24];

        float selfnext = 0.0f;
        if (tid < FD) selfnext = nf[(size_t)n1 * FD + tid];

        const int mr = s_nl[pb][32];
        const int m  = (mr > MAXDEG) ? MAXDEG : mr;

        // ---- topk: per-column top-8 (desc) with zero-pad rule; write selT ----
        if (tid < FD) {
            const int d = tid;
            const float NEG = -__builtin_inff();
            float tk[8];
#pragma unroll
            for (int r = 0; r < 8; ++r) tk[r] = NEG;
            const float* gcol = s_g + pb * (MAXDEG * FD) + d;
            for (int j = 0; j < m; ++j) {
                float v = gcol[j * FD];
#pragma unroll
                for (int r = 0; r < 8; ++r) {   // sorted insertion
                    const float hi = fmaxf(tk[r], v);
                    v = fminf(tk[r], v);
                    tk[r] = hi;
                }
            }
            if (m < KTOP) {   // wave-uniform, practically never taken
#pragma unroll
                for (int r = 0; r < 8; ++r) tk[r] = (tk[r] == NEG) ? 0.0f : tk[r];
#pragma unroll
                for (int pass = 0; pass < 8; ++pass)
#pragma unroll
                    for (int r = 0; r < 7; ++r) {
                        const float hi = fmaxf(tk[r], tk[r + 1]);
                        const float lo = fminf(tk[r], tk[r + 1]);
                        tk[r] = hi; tk[r + 1] = lo;
                    }
            }
            // row d of sel^T: [self, t0..t7, 0 x 15]
            const unsigned p01 = (unsigned)f2bf(selfv) | ((unsigned)f2bf(tk[0]) << 16);
            const unsigned p23 = (unsigned)f2bf(tk[1]) | ((unsigned)f2bf(tk[2]) << 16);
            const unsigned p45 = (unsigned)f2bf(tk[3]) | ((unsigned)f2bf(tk[4]) << 16);
            const unsigned p67 = (unsigned)f2bf(tk[5]) | ((unsigned)f2bf(tk[6]) << 16);
            const unsigned p8  = (unsigned)f2bf(tk[7]);
            uint4* dst = (uint4*)&s_selT[d * SELT_STRIDE];
            dst[0] = make_uint4(p01, p23, p45, p67);
            dst[1] = make_uint4(p8, 0, 0, 0);
            dst[2] = make_uint4(0, 0, 0, 0);
        }

        BAR_LGKM();   // bar2: selT ready; next-buffer writes may start

        // ---- stage next node's gather + list into LDS (before stores so the
        //      vmcnt wait here only covers the gather loads, not 64 stores) ----
        {
            float4* gd = (float4*)(s_g + (pb ^ 1) * (MAXDEG * FD) + gj * FD);
            gd[gl] = a0; gd[gl + 8] = a1; gd[gl + 16] = a2; gd[gl + 24] = a3;
            if (tid < 33) s_nl[pb][tid] = nlv;
        }

        // ---- MFMA: C = W' * S; B-frag = one aligned ds_read_b128 ----
        f32x4 acc[4][4];
#pragma unroll
        for (int mt = 0; mt < 4; ++mt)
#pragma unroll
            for (int nt = 0; nt < 4; ++nt) acc[mt][nt] = bias[mt];

#pragma unroll
        for (int s = 0; s < 5; ++s) {
            const int t = 2 * s + (q >> 1);
            const int c0 = (q & 1) * 8;
            short8 bfrag[4];
#pragma unroll
            for (int nt = 0; nt < 4; ++nt) {
                const int n = (nh * 4 + nt) * 16 + n16;
                bfrag[nt] = *(const short8*)&s_selT[(n + t) * SELT_STRIDE + c0];
            }
#pragma unroll
            for (int mt = 0; mt < 4; ++mt)
#pragma unroll
                for (int nt = 0; nt < 4; ++nt)
                    acc[mt][nt] = __builtin_amdgcn_mfma_f32_16x16x32_bf16(
                        afrag[mt][s], bfrag[nt], acc[mt][nt], 0, 0, 0);
        }

        // ---- epilogue store ----
        float* const op = out + (size_t)node * (OUT_CH * XOUT);
#pragma unroll
        for (int mt = 0; mt < 4; ++mt) {
            const int ob = (mh * 4 + mt) * 16 + q * 4;
#pragma unroll
            for (int nt = 0; nt < 4; ++nt) {
                const int x = (nh * 4 + nt) * 16 + n16;
                if (x < XOUT) {
#pragma unroll
                    for (int r = 0; r < 4; ++r)
                        op[(size_t)(ob + r) * XOUT + x] = acc[mt][nt][r];
                }
            }
        }

        selfv = selfnext;
        pb ^= 1;
    }
}

// ---------------------------------------------------------------------------
// Fallback: previous fused kernel (verified 983 µs) — used if ws too small.
// ---------------------------------------------------------------------------
__global__ __launch_bounds__(256, 2)
void lgcl_fused(const float* __restrict__ nf, const int* __restrict__ adj,
                const float* __restrict__ cw, const float* __restrict__ cb,
                float* __restrict__ out)
{
    __shared__ int s_cnt;
    __shared__ int s_nbr[MAXDEG];
    __shared__ float s_g[MAXDEG * FD];
    __shared__ unsigned short s_selT[SELT_ROWS * SELT_STRIDE];

    const int tid = threadIdx.x;
    const int lane = tid & 63;
    const int wv  = tid >> 6;
    const int q   = lane >> 4;
    const int n16 = lane & 15;
    const int mh  = wv >> 1;
    const int nh  = wv & 1;

    short8 afrag[4][5];
#pragma unroll
    for (int mt = 0; mt < 4; ++mt) {
        const int o = (mh * 4 + mt) * 16 + n16;
#pragma unroll
        for (int s = 0; s < 5; ++s) {
            const int t = 2 * s + (q >> 1);
            const int c0 = (q & 1) * 8;
            short8 a;
#pragma unroll
            for (int j = 0; j < 8; ++j) {
                const int c = c0 + j;
                float v = 0.0f;
                if (c <= 8 && t <= 8) v = cw[(o * 9 + c) * 9 + t];
                a[j] = (short)f2bf(v);
            }
            afrag[mt][s] = a;
        }
    }
    f32x4 bias[4];
#pragma unroll
    for (int mt = 0; mt < 4; ++mt) {
        const int o = (mh * 4 + mt) * 16 + q * 4;
        f32x4 b;
        b[0] = cb[o]; b[1] = cb[o + 1]; b[2] = cb[o + 2]; b[3] = cb[o + 3];
        bias[mt] = b;
    }

    if (tid >= 128 && tid < 128 + (SELT_ROWS - FD)) {
        uint4* p = (uint4*)&s_selT[tid * SELT_STRIDE];
        p[0] = make_uint4(0, 0, 0, 0);
        p[1] = make_uint4(0, 0, 0, 0);
        p[2] = make_uint4(0, 0, 0, 0);
    }

    for (int node = blockIdx.x; node < NNODES; node += gridDim.x) {
        if (tid == 0) s_cnt = 0;
        __syncthreads();

        const int4* arow = (const int4*)(adj + (size_t)node * NNODES);
        for (int i = tid; i < NNODES / 4; i += 256) {
            const int4 v = arow[i];
            if (v.x == 1) { int p = atomicAdd(&s_cnt, 1); if (p < MAXDEG) s_nbr[p] = 4 * i + 0; }
            if (v.y == 1) { int p = atomicAdd(&s_cnt, 1); if (p < MAXDEG) s_nbr[p] = 4 * i + 1; }
            if (v.z == 1) { int p = atomicAdd(&s_cnt, 1); if (p < MAXDEG) s_nbr[p] = 4 * i + 2; }
            if (v.w == 1) { int p = atomicAdd(&s_cnt, 1); if (p < MAXDEG) s_nbr[p] = 4 * i + 3; }
        }
        __syncthreads();
        int m = s_cnt; if (m > MAXDEG) m = MAXDEG;

        {
            const int j = tid >> 3, l8 = tid & 7;
            if (j < m) {
                const float4* src = (const float4*)(nf + (size_t)s_nbr[j] * FD);
                float4* dst = (float4*)(s_g + j * FD);
#pragma unroll
                for (int u = 0; u < 4; ++u) dst[l8 + 8 * u] = src[l8 + 8 * u];
            }
        }
        __syncthreads();

        if (tid < FD) {
            const int d = tid;
            const float NEG = -__builtin_inff();
            float tk[8];
#pragma unroll
            for (int r = 0; r < 8; ++r) tk[r] = NEG;
            for (int j = 0; j < m; ++j) {
                float v = s_g[j * FD + d];
#pragma unroll
                for (int r = 0; r < 8; ++r) {
                    const float hi = fmaxf(tk[r], v);
                    v = fminf(tk[r], v);
                    tk[r] = hi;
                }
            }
            if (m < KTOP) {
#pragma unroll
                for (int r = 0; r < 8; ++r) tk[r] = (tk[r] == NEG) ? 0.0f : tk[r];
#pragma unroll
                for (int pass = 0; pass < 8; ++pass)
#pragma unroll
                    for (int r = 0; r < 7; ++r) {
                        const float hi = fmaxf(tk[r], tk[r + 1]);
                        const float lo = fminf(tk[r], tk[r + 1]);
                        tk[r] = hi; tk[r + 1] = lo;
                    }
            }
            const float self = nf[(size_t)node * FD + d];
            const unsigned p01 = (unsigned)f2bf(self)  | ((unsigned)f2bf(tk[0]) << 16);
            const unsigned p23 = (unsigned)f2bf(tk[1]) | ((unsigned)f2bf(tk[2]) << 16);
            const unsigned p45 = (unsigned)f2bf(tk[3]) | ((unsigned)f2bf(tk[4]) << 16);
            const unsigned p67 = (unsigned)f2bf(tk[5]) | ((unsigned)f2bf(tk[6]) << 16);
            const unsigned p8  = (unsigned)f2bf(tk[7]);
            uint4* dst = (uint4*)&s_selT[d * SELT_STRIDE];
            dst[0] = make_uint4(p01, p23, p45, p67);
            dst[1] = make_uint4(p8, 0, 0, 0);
            dst[2] = make_uint4(0, 0, 0, 0);
        }
        __syncthreads();

        f32x4 acc[4][4];
#pragma unroll
        for (int mt = 0; mt < 4; ++mt)
#pragma unroll
            for (int nt = 0; nt < 4; ++nt) acc[mt][nt] = bias[mt];

#pragma unroll
        for (int s = 0; s < 5; ++s) {
            const int t = 2 * s + (q >> 1);
            const int c0 = (q & 1) * 8;
            short8 bfrag[4];
#pragma unroll
            for (int nt = 0; nt < 4; ++nt) {
                const int n = (nh * 4 + nt) * 16 + n16;
                bfrag[nt] = *(const short8*)&s_selT[(n + t) * SELT_STRIDE + c0];
            }
#pragma unroll
            for (int mt = 0; mt < 4; ++mt)
#pragma unroll
                for (int nt = 0; nt < 4; ++nt)
                    acc[mt][nt] = __builtin_amdgcn_mfma_f32_16x16x32_bf16(
                        afrag[mt][s], bfrag[nt], acc[mt][nt], 0, 0, 0);
        }

        float* const op = out + (size_t)node * (OUT_CH * XOUT);
#pragma unroll
        for (int mt = 0; mt < 4; ++mt) {
            const int ob = (mh * 4 + mt) * 16 + q * 4;
#pragma unroll
            for (int nt = 0; nt < 4; ++nt) {
                const int x = (nh * 4 + nt) * 16 + n16;
                if (x < XOUT) {
#pragma unroll
                    for (int r = 0; r < 4; ++r)
                        op[(size_t)(ob + r) * XOUT + x] = acc[mt][nt][r];
                }
            }
        }
    }
}

extern "C" void kernel_launch(void* const* d_in, const int* in_sizes, int n_in,
                              void* d_out, int out_size, void* d_ws, size_t ws_size,
                              hipStream_t stream)
{
    (void)in_sizes; (void)n_in; (void)out_size;
    const float* nf  = (const float*)d_in[0];
    const int*   adj = (const int*)d_in[1];
    const float* cw  = (const float*)d_in[2];
    const float* cb  = (const float*)d_in[3];
    float* out = (float*)d_out;

    if (d_ws != nullptr && ws_size >= WS_NEEDED) {
        int* nbr = (int*)d_ws;
        int* cnt = nbr + (size_t)NNODES * MAXDEG;
        // A: 2500 blocks x 4 waves = 10000 waves, one adjacency row each.
        lgcl_scan<<<dim3(2500), dim3(256), 0, stream>>>(adj, nbr, cnt);
        // B: 512 blocks = 2/CU; ~20 nodes per block, 2-deep node pipeline.
        lgcl_conv<<<dim3(512), dim3(256), 0, stream>>>(nf, nbr, cnt, cw, cb, out);
    } else {
        lgcl_fused<<<dim3(512), dim3(256), 0, stream>>>(nf, adj, cw, cb, out);
    }
}